// Round 16
// baseline (134.295 us; speedup 1.0000x reference)
//
#include <hip/hip_runtime.h>
#include <stdint.h>

// SNN forward (Mozafari 2018), max_layer==2:
//   pad(2) -> conv1(30,6,5,5) -> fire(>15) -> maxpool2x2 -> pad(1)
//   -> conv2(240,30,3,3) -> fire(>10) -> out = spk ++ pot (f32)
//
// R1: no hipMemsetAsync. R2: ring-only zero. R3 probe: conv2 ~114 us.
// R4: XCD swizzle regressed, reverted.
// R5: conv2 transposed epilogue (1KB contiguous store runs): -33.5 -> 132.6.
// R6/R7: conv2 A-in-LDS + B-global bundle regressed, reverted.
// R8 probe: conv1 ~32 us. R9: conv1 SW-pipeline + (256,4): null.
// R10 probe: conv2 memory-bound; write stream thrashes caches.
// R11/R12: conv2 NT stores: -4.2 -> 128.4. conv2 ~76 us (locked).
// R13 probe: conv1 = 33.6 us, MfmaUtil 15%, VALU 11%, Occ 44%, tiny
//     FETCH/WRITE -> memory-LATENCY-bound, too few outstanding loads.
// R14: conv2 B-from-global: regressed, reverted. R15: prep vectorized: -1.9.
// R16: conv1 M=128/wave (8 chunks of 16 rows, grid 1470): doubles
//     independent A-gathers in flight per wave (2x MLP), each B ds-load
//     feeds 8 MFMAs, VMEM insts/row -20%. Dropped null R9 pipeline +
//     (256,4) bound (VGPR ~145 -> ~3 waves/SIMD; outstanding loads/CU
//     56 -> ~96). Targets the latency bound the R13 counters exposed.

typedef _Float16 half8  __attribute__((ext_vector_type(8)));
typedef _Float16 half8u __attribute__((ext_vector_type(8), aligned(4)));
typedef float f32x4  __attribute__((ext_vector_type(4)));
typedef float f32x4u __attribute__((ext_vector_type(4), aligned(4)));
typedef float f32x2  __attribute__((ext_vector_type(2)));
typedef short s16x4  __attribute__((ext_vector_type(4)));
typedef short s16x4u __attribute__((ext_vector_type(4), aligned(2)));

#define POT1_T 15.0f
#define POT2_T 10.0f

// ---- ws layout (all 16B aligned) ----
#define SPK_ELEMS  (15*114*114*32)            // 6,238,080 f16 (ch-interleaved, padded)
#define SPK_BYTES  (SPK_ELEMS*2)              // 12,476,160
#define BP2_OFF    SPK_BYTES
#define BP2_BYTES  (9*15*64*8*2)              // 138,240
#define BP1_OFF    (BP2_OFF + BP2_BYTES)
#define BP1_BYTES  (8*2*64*8*2)               // 16,384
#define IN16_OFF   (BP1_OFF + BP1_BYTES)      // 12,630,784 (16B aligned)
#define IN16_ELEMS (90*228*228)               // 4,678,560 f16 per copy
// ina at IN16_OFF; inb (shifted copy) right after; +16B guard. ~31.3 MB total.

#define ROWS_TOTAL (90*228)                   // 20,520 padded rows
#define PADROW_BLOCKS (ROWS_TOTAL/4)          // 5130 (4 waves/block, 1 row/wave)
// pool-pad ring of spike map: 452 positions/image x 32 ch x 15 images
#define RING_ELEMS (15*452*32)                // 216,960
#define RING_BLOCKS ((RING_ELEMS + 255) / 256) // 848

__device__ __forceinline__ unsigned short f2h(float v) {
  union { _Float16 h; unsigned short u; } c;
  c.h = (_Float16)v;                          // RNE
  return c.u;
}

// ---------------------------------------------------------------------------
// prep: pad input -> f16 dual copies (ina[i]=v(i), inb[i-1]=v(i)), zero the
// spike-map pad ring, weight packing to MFMA B-frag layout.
// R15: pad path is one WAVE per padded row; lane l covers xx = 4l..4l+3.
// ---------------------------------------------------------------------------
__global__ __launch_bounds__(256) void prep(
    const float* __restrict__ in, const float* __restrict__ w1,
    const float* __restrict__ w2, unsigned short* __restrict__ ina,
    unsigned short* __restrict__ bp2, unsigned short* __restrict__ bp1,
    unsigned short* __restrict__ spk16)
{
  const int blk = blockIdx.x;
  if (blk < PADROW_BLOCKS) {
    const int wave = threadIdx.x >> 6, l = threadIdx.x & 63;
    if (l >= 57) return;                      // 57 lanes cover 228 = 57*4
    const int row = blk * 4 + wave;           // padded row index (c*228+yy)
    const int c = row / 228, yy = row % 228;
    const int xx0 = l * 4;
    const int rowbase = row * 228;
    s16x4 h4 = (s16x4){0, 0, 0, 0};
    if (yy >= 2 && yy < 226) {
      const float* src = in + ((c * 224 + (yy - 2)) * 224) - 2;  // src[xx]=in[..,xx-2]
      if (l >= 1 && l <= 55) {
        const f32x4u v = *(const f32x4u*)(src + xx0);
        #pragma unroll
        for (int j = 0; j < 4; ++j) h4[j] = (short)f2h(v[j]);
      } else {                                // l==0 (xx 0..3) or l==56 (xx 224..227)
        #pragma unroll
        for (int j = 0; j < 4; ++j) {
          const int xx = xx0 + j;
          if (xx >= 2 && xx < 226) h4[j] = (short)f2h(src[xx]);
        }
      }
    }
    unsigned short* inb = ina + IN16_ELEMS;
    *(s16x4*)(ina + rowbase + xx0) = h4;
    if (row == 0 && l == 0) {                 // avoid inb[-1]
      inb[0] = (unsigned short)h4[1];
      inb[1] = (unsigned short)h4[2];
      inb[2] = (unsigned short)h4[3];
    } else {
      *(s16x4u*)(inb + rowbase + xx0 - 1) = h4;
    }
    if (row == ROWS_TOTAL - 1 && l == 56) inb[IN16_ELEMS - 1] = 0;
    return;
  }
  if (blk < PADROW_BLOCKS + RING_BLOCKS) {    // zero the pool-pad ring only
    const int i = (blk - PADROW_BLOCKS) * 256 + threadIdx.x;
    if (i >= RING_ELEMS) return;
    const int ch = i & 31, t = i >> 5;
    const int p = t % 452, n = t / 452;
    int y, x;
    if (p < 114)      { y = 0;       x = p; }
    else if (p < 228) { y = 113;     x = p - 114; }
    else if (p < 340) { y = p - 227; x = 0; }     // y = 1..112
    else              { y = p - 339; x = 113; }   // y = 1..112
    spk16[((size_t)(n * 114 + y) * 114 + x) * 32 + ch] = 0;
    return;
  }
  if (threadIdx.x >= 64) return;
  const int b = blk - PADROW_BLOCKS - RING_BLOCKS; // 0..150
  const int lane = threadIdx.x;
  const int quad = lane >> 4, nl = lane & 15;
  if (b < 135) {                               // conv2: 9 steps x 15 nsub
    const int s = b / 15, nsub = b - s * 15;   // s = ky*3+kx
    const int ch = nsub * 16 + nl;
    unsigned short* dst = bp2 + (((s * 15 + nsub) * 64 + lane) << 3);
    #pragma unroll
    for (int j = 0; j < 8; ++j) {
      const int ci = quad * 8 + j;
      dst[j] = f2h((ci < 30) ? w2[ch * 270 + ci * 9 + s] : 0.0f);
    }
  } else {                                     // conv1: 8 steps x 2 nsub
    const int bb = b - 135;
    const int s = bb >> 1, nsub = bb & 1;
    const int ch = nsub * 16 + nl;
    unsigned short* dst = bp1 + (((s * 2 + nsub) * 64 + lane) << 3);
    #pragma unroll
    for (int j = 0; j < 8; ++j) {
      int ci, ky;
      bool ok = (ch < 30) && (j < 5);
      if (s < 6)       { ci = s;        ky = quad; }
      else if (s == 6) { ci = quad;     ky = 4;    }
      else             { ci = 4 + quad; ky = 4; ok = ok && (quad < 2); }
      float v = 0.0f;
      if (ok) v = w1[ch * 150 + ci * 25 + ky * 5 + j];
      dst[j] = f2h(v);
    }
  }
}

// ---------------------------------------------------------------------------
// conv1 + fire + maxpool2x2. Pool-interleaved M. R16: M=128 per wave —
// 8 chunks of 16 rows share each B-frag (2x MLP: 8 independent A-gathers
// in flight; each B ds-load feeds 8 MFMAs). grid 1470 x 256. No LDS.
// A-frag = one 4B-aligned b128 from the parity-matched input copy
// (parity = nl&1; m0, c*16 even).
// ---------------------------------------------------------------------------
__global__ __launch_bounds__(256) void conv1_mfma(
    const unsigned short* __restrict__ in16,   // ina; inb = ina + IN16_ELEMS
    const unsigned short* __restrict__ bp1,
    unsigned short* __restrict__ spk16)
{
  const int tid = threadIdx.x;
  const int wave = tid >> 6, lane = tid & 63;
  const int quad = lane >> 4, nl = lane & 15;
  const int m0 = blockIdx.x * 512 + wave * 128;

  const unsigned short* base = in16 + ((nl & 1) ? (IN16_ELEMS - 1) : 0);

  unsigned o_q[8], o_a[8], o_b[8];
  #pragma unroll
  for (int c = 0; c < 8; ++c) {
    const int m = m0 + c * 16 + nl;
    const int sub = m & 3, g = m >> 2;
    const int gx = g % 112, t = g / 112;
    const int gy = t % 112, n = t / 112;
    const int y0 = gy * 2 + (sub >> 1);        // padded coords
    const int x0 = gx * 2 + (sub & 1);
    const unsigned nb = (unsigned)n * 311904u; // 6*51984
    o_q[c] = nb + (unsigned)((y0 + quad) * 228 + x0);
    o_a[c] = nb + (unsigned)quad * 51984u + (unsigned)((y0 + 4) * 228 + x0);
    o_b[c] = nb + (unsigned)(4 + (quad & 1)) * 51984u + (unsigned)((y0 + 4) * 228 + x0);
  }

  f32x4 acc[8][2];
  #pragma unroll
  for (int c = 0; c < 8; ++c) {
    acc[c][0] = (f32x4){0.f, 0.f, 0.f, 0.f};
    acc[c][1] = (f32x4){0.f, 0.f, 0.f, 0.f};
  }

  const half8* bptr = (const half8*)bp1;
  #pragma unroll
  for (int s = 0; s < 8; ++s) {
    const half8 b0 = bptr[(s * 2 + 0) * 64 + lane];
    const half8 b1 = bptr[(s * 2 + 1) * 64 + lane];
    #pragma unroll
    for (int c = 0; c < 8; ++c) {
      const unsigned off = (s < 6) ? (o_q[c] + (unsigned)s * 51984u)
                                   : (s == 6 ? o_a[c] : o_b[c]);
      const half8 A = *(const half8u*)(base + off);
      acc[c][0] = __builtin_amdgcn_mfma_f32_16x16x32_f16(A, b0, acc[c][0], 0, 0, 0);
      acc[c][1] = __builtin_amdgcn_mfma_f32_16x16x32_f16(A, b1, acc[c][1], 0, 0, 0);
    }
  }

  #pragma unroll
  for (int c = 0; c < 8; ++c) {
    const int gq = ((m0 + c * 16) >> 2) + quad;
    const int pgx = gq % 112, tq = gq / 112;
    const int pgy = tq % 112, nq = tq / 112;
    const bool f0 = (acc[c][0][0] > POT1_T) | (acc[c][0][1] > POT1_T) |
                    (acc[c][0][2] > POT1_T) | (acc[c][0][3] > POT1_T);
    const bool f1 = (acc[c][1][0] > POT1_T) | (acc[c][1][1] > POT1_T) |
                    (acc[c][1][2] > POT1_T) | (acc[c][1][3] > POT1_T);
    const size_t o = ((size_t)(nq * 114 + pgy + 1) * 114 + (pgx + 1)) * 32 + nl;
    spk16[o] = f0 ? (unsigned short)0x3C00 : (unsigned short)0;
    // ch nl+16: 30/31 (nl>=14) are always zero — written unconditionally so
    // the whole interior is produced here (prep only zeroes the pad ring).
    spk16[o + 16] = (nl < 14 && f1) ? (unsigned short)0x3C00 : (unsigned short)0;
  }
}

// ---------------------------------------------------------------------------
// conv2 + fire (R12 form — locked): block = 4 waves x M=256 rows; N = 5
// subtiles (80 ch), gridDim.y = 3. B staged in LDS (46 KB); each
// ds_read_b128 of B feeds 4 MFMAs. grid (735, 3) x 256.
// R5 epilogue: per u-subtile LDS transpose; every store = one 1KB run.
// R11/R12: nontemporal output stores.
// ---------------------------------------------------------------------------
#define C2_NSUB 5
#define TPAD 258   // f32 stride per ch row: even (b64-aligned)
__global__ __launch_bounds__(256, 3) void conv2_mfma(
    const unsigned short* __restrict__ spk16,
    const unsigned short* __restrict__ bp2,
    float* __restrict__ out_spk, float* __restrict__ out_pot)
{
  __shared__ __attribute__((aligned(16))) unsigned short Blds[C2_NSUB * 9 * 64 * 8];

  const int tid = threadIdx.x;
  const int ntile = blockIdx.y;                // 0..2, subtiles ntile*5..+4
  // stage 5 subtiles x 9 steps x 64 lanes x 16B = 2880 uint4
  for (int i = tid; i < 2880; i += 256) {
    const int su = i / 576, rem = i - su * 576;    // rem = s*64+lane
    ((uint4*)Blds)[su * 576 + rem] =
        ((const uint4*)bp2)[((rem >> 6) * 15 + ntile * C2_NSUB + su) * 64 + (rem & 63)];
  }
  __syncthreads();

  const int wave = tid >> 6, lane = tid & 63;
  const int quad = lane >> 4, nl = lane & 15;
  const int bx = blockIdx.x;
  const int m0 = bx * 256 + wave * 64;

  const unsigned short* abase[4];
  #pragma unroll
  for (int c = 0; c < 4; ++c) {
    const int m = m0 + c * 16 + nl;
    const int x = m % 112, t = m / 112;
    const int y = t % 112, n = t / 112;
    abase[c] = spk16 + ((size_t)(n * 114 + y) * 114 + x) * 32 + quad * 8;
  }

  f32x4 acc[4][C2_NSUB];
  #pragma unroll
  for (int c = 0; c < 4; ++c)
    #pragma unroll
    for (int u = 0; u < C2_NSUB; ++u) acc[c][u] = (f32x4){0.f, 0.f, 0.f, 0.f};

  const half8* blds = (const half8*)Blds;
  #pragma unroll
  for (int s = 0; s < 9; ++s) {                // s = ky*3+kx
    const int ky = s / 3, kx = s - ky * 3;     // compile-time under unroll
    half8 a[4];
    #pragma unroll
    for (int c = 0; c < 4; ++c)
      a[c] = *(const half8*)(abase[c] + (ky * 114 + kx) * 32);
    #pragma unroll
    for (int u = 0; u < C2_NSUB; ++u) {
      const half8 b = blds[(u * 9 + s) * 64 + lane];
      #pragma unroll
      for (int c = 0; c < 4; ++c)
        acc[c][u] = __builtin_amdgcn_mfma_f32_16x16x32_f16(a[c], b, acc[c][u], 0, 0, 0);
    }
  }

  // ---- transposed epilogue (R5) + nontemporal stores (R11) ----
  float* T = (float*)Blds;                     // 16 x TPAD f32, reuses Blds
  const int n   = (bx * 256) / 12544;
  const int ip0 = (bx * 256) % 12544;
  const size_t obase = (size_t)n * 240 * 12544 + ip0 + 4 * lane;

  #pragma unroll
  for (int u = 0; u < C2_NSUB; ++u) {
    __syncthreads();                           // prev round's reads done
    #pragma unroll
    for (int c = 0; c < 4; ++c) {
      const int mb = wave * 64 + c * 16 + quad * 4;
      #pragma unroll
      for (int rr = 0; rr < 4; ++rr)
        T[nl * TPAD + mb + rr] = acc[c][u][rr];
    }
    __syncthreads();
    #pragma unroll
    for (int j = 0; j < 4; ++j) {
      const int chl = wave * 4 + j;            // 0..15 across 4 waves
      const int ch  = (ntile * C2_NSUB + u) * 16 + chl;
      const f32x2 lo = *(const f32x2*)&T[chl * TPAD + 4 * lane];
      const f32x2 hi = *(const f32x2*)&T[chl * TPAD + 4 * lane + 2];
      f32x4 pt, sp;
      pt[0] = lo[0]; pt[1] = lo[1]; pt[2] = hi[0]; pt[3] = hi[1];
      #pragma unroll
      for (int rr = 0; rr < 4; ++rr) {
        const bool f = pt[rr] > POT2_T;
        sp[rr] = f ? 1.0f : 0.0f;
        pt[rr] = f ? pt[rr] : 0.0f;
      }
      const size_t o = obase + (size_t)ch * 12544;
      __builtin_nontemporal_store(sp, (f32x4*)(out_spk + o));
      __builtin_nontemporal_store(pt, (f32x4*)(out_pot + o));
    }
  }
}

// ---------------------------------------------------------------------------
extern "C" void kernel_launch(void* const* d_in, const int* in_sizes, int n_in,
                              void* d_out, int out_size, void* d_ws, size_t ws_size,
                              hipStream_t stream)
{
  const float* in = (const float*)d_in[0];
  const float* w1 = (const float*)d_in[1];
  const float* w2 = (const float*)d_in[2];
  float* out = (float*)d_out;

  unsigned short* spk16 = (unsigned short*)d_ws;
  unsigned short* bp2   = (unsigned short*)((char*)d_ws + BP2_OFF);
  unsigned short* bp1   = (unsigned short*)((char*)d_ws + BP1_OFF);
  unsigned short* ina   = (unsigned short*)((char*)d_ws + IN16_OFF);

  prep<<<PADROW_BLOCKS + RING_BLOCKS + 151, 256, 0, stream>>>(
      in, w1, w2, ina, bp2, bp1, spk16);
  conv1_mfma<<<1470, 256, 0, stream>>>(ina, bp1, spk16);
  conv2_mfma<<<dim3(735, 3), 256, 0, stream>>>(
      spk16, bp2, out, out + (size_t)15 * 240 * 112 * 112);
}

// Round 17
// 129.186 us; speedup vs baseline: 1.0396x; 1.0396x over previous
//
#include <hip/hip_runtime.h>
#include <stdint.h>

// SNN forward (Mozafari 2018), max_layer==2:
//   pad(2) -> conv1(30,6,5,5) -> fire(>15) -> maxpool2x2 -> pad(1)
//   -> conv2(240,30,3,3) -> fire(>10) -> out = spk ++ pot (f32)
//
// R1: no hipMemsetAsync. R2: ring-only zero. R3 probe: conv2 ~114 us.
// R4: XCD swizzle regressed. R5: transposed epilogue -33.5 -> 132.6.
// R6/R7: conv2 A-in-LDS regressed. R8 probe: conv1 ~32 us.
// R9: conv1 SW-pipeline + (256,4): null (kept in R15 form).
// R10 probe: conv2 memory-bound. R11/R12: NT stores -4.2 -> 128.4.
// R13 probe: conv1 latency-bound scatter, no pipe >16% (structural).
// R14: conv2 B-from-global regressed (B-LDS load-bearing).
// R15: prep vectorized 4-wide: -1.9 -> 126.5 (best).
// R16: conv1 M=128/wave regressed (+7.8, VGPR pressure) — REVERTED.
// R17: conv2 C2_NSUB 5->3 (gridDim.y 5): LDS 46->27.6 KB -> occupancy
//     3 -> 5 blocks/CU (+66% resident waves / outstanding NT stores).
//     B-LDS kept (R14 showed it's load-bearing); only N-partition changes.
//     Cost: A-tile re-read x5/3 — betting store-concurrency > read growth.

typedef _Float16 half8  __attribute__((ext_vector_type(8)));
typedef _Float16 half8u __attribute__((ext_vector_type(8), aligned(4)));
typedef float f32x4  __attribute__((ext_vector_type(4)));
typedef float f32x4u __attribute__((ext_vector_type(4), aligned(4)));
typedef float f32x2  __attribute__((ext_vector_type(2)));
typedef short s16x4  __attribute__((ext_vector_type(4)));
typedef short s16x4u __attribute__((ext_vector_type(4), aligned(2)));

#define POT1_T 15.0f
#define POT2_T 10.0f

// ---- ws layout (all 16B aligned) ----
#define SPK_ELEMS  (15*114*114*32)            // 6,238,080 f16 (ch-interleaved, padded)
#define SPK_BYTES  (SPK_ELEMS*2)              // 12,476,160
#define BP2_OFF    SPK_BYTES
#define BP2_BYTES  (9*15*64*8*2)              // 138,240
#define BP1_OFF    (BP2_OFF + BP2_BYTES)
#define BP1_BYTES  (8*2*64*8*2)               // 16,384
#define IN16_OFF   (BP1_OFF + BP1_BYTES)      // 12,630,784 (16B aligned)
#define IN16_ELEMS (90*228*228)               // 4,678,560 f16 per copy
// ina at IN16_OFF; inb (shifted copy) right after; +16B guard. ~31.3 MB total.

#define ROWS_TOTAL (90*228)                   // 20,520 padded rows
#define PADROW_BLOCKS (ROWS_TOTAL/4)          // 5130 (4 waves/block, 1 row/wave)
// pool-pad ring of spike map: 452 positions/image x 32 ch x 15 images
#define RING_ELEMS (15*452*32)                // 216,960
#define RING_BLOCKS ((RING_ELEMS + 255) / 256) // 848

__device__ __forceinline__ unsigned short f2h(float v) {
  union { _Float16 h; unsigned short u; } c;
  c.h = (_Float16)v;                          // RNE
  return c.u;
}

// ---------------------------------------------------------------------------
// prep: pad input -> f16 dual copies (ina[i]=v(i), inb[i-1]=v(i)), zero the
// spike-map pad ring, weight packing to MFMA B-frag layout.
// R15: pad path is one WAVE per padded row; lane l covers xx = 4l..4l+3.
// ---------------------------------------------------------------------------
__global__ __launch_bounds__(256) void prep(
    const float* __restrict__ in, const float* __restrict__ w1,
    const float* __restrict__ w2, unsigned short* __restrict__ ina,
    unsigned short* __restrict__ bp2, unsigned short* __restrict__ bp1,
    unsigned short* __restrict__ spk16)
{
  const int blk = blockIdx.x;
  if (blk < PADROW_BLOCKS) {
    const int wave = threadIdx.x >> 6, l = threadIdx.x & 63;
    if (l >= 57) return;                      // 57 lanes cover 228 = 57*4
    const int row = blk * 4 + wave;           // padded row index (c*228+yy)
    const int c = row / 228, yy = row % 228;
    const int xx0 = l * 4;
    const int rowbase = row * 228;
    s16x4 h4 = (s16x4){0, 0, 0, 0};
    if (yy >= 2 && yy < 226) {
      const float* src = in + ((c * 224 + (yy - 2)) * 224) - 2;  // src[xx]=in[..,xx-2]
      if (l >= 1 && l <= 55) {
        const f32x4u v = *(const f32x4u*)(src + xx0);
        #pragma unroll
        for (int j = 0; j < 4; ++j) h4[j] = (short)f2h(v[j]);
      } else {                                // l==0 (xx 0..3) or l==56 (xx 224..227)
        #pragma unroll
        for (int j = 0; j < 4; ++j) {
          const int xx = xx0 + j;
          if (xx >= 2 && xx < 226) h4[j] = (short)f2h(src[xx]);
        }
      }
    }
    unsigned short* inb = ina + IN16_ELEMS;
    *(s16x4*)(ina + rowbase + xx0) = h4;
    if (row == 0 && l == 0) {                 // avoid inb[-1]
      inb[0] = (unsigned short)h4[1];
      inb[1] = (unsigned short)h4[2];
      inb[2] = (unsigned short)h4[3];
    } else {
      *(s16x4u*)(inb + rowbase + xx0 - 1) = h4;
    }
    if (row == ROWS_TOTAL - 1 && l == 56) inb[IN16_ELEMS - 1] = 0;
    return;
  }
  if (blk < PADROW_BLOCKS + RING_BLOCKS) {    // zero the pool-pad ring only
    const int i = (blk - PADROW_BLOCKS) * 256 + threadIdx.x;
    if (i >= RING_ELEMS) return;
    const int ch = i & 31, t = i >> 5;
    const int p = t % 452, n = t / 452;
    int y, x;
    if (p < 114)      { y = 0;       x = p; }
    else if (p < 228) { y = 113;     x = p - 114; }
    else if (p < 340) { y = p - 227; x = 0; }     // y = 1..112
    else              { y = p - 339; x = 113; }   // y = 1..112
    spk16[((size_t)(n * 114 + y) * 114 + x) * 32 + ch] = 0;
    return;
  }
  if (threadIdx.x >= 64) return;
  const int b = blk - PADROW_BLOCKS - RING_BLOCKS; // 0..150
  const int lane = threadIdx.x;
  const int quad = lane >> 4, nl = lane & 15;
  if (b < 135) {                               // conv2: 9 steps x 15 nsub
    const int s = b / 15, nsub = b - s * 15;   // s = ky*3+kx
    const int ch = nsub * 16 + nl;
    unsigned short* dst = bp2 + (((s * 15 + nsub) * 64 + lane) << 3);
    #pragma unroll
    for (int j = 0; j < 8; ++j) {
      const int ci = quad * 8 + j;
      dst[j] = f2h((ci < 30) ? w2[ch * 270 + ci * 9 + s] : 0.0f);
    }
  } else {                                     // conv1: 8 steps x 2 nsub
    const int bb = b - 135;
    const int s = bb >> 1, nsub = bb & 1;
    const int ch = nsub * 16 + nl;
    unsigned short* dst = bp1 + (((s * 2 + nsub) * 64 + lane) << 3);
    #pragma unroll
    for (int j = 0; j < 8; ++j) {
      int ci, ky;
      bool ok = (ch < 30) && (j < 5);
      if (s < 6)       { ci = s;        ky = quad; }
      else if (s == 6) { ci = quad;     ky = 4;    }
      else             { ci = 4 + quad; ky = 4; ok = ok && (quad < 2); }
      float v = 0.0f;
      if (ok) v = w1[ch * 150 + ci * 25 + ky * 5 + j];
      dst[j] = f2h(v);
    }
  }
}

// ---------------------------------------------------------------------------
// conv1 + fire + maxpool2x2 (R15-exact). Pool-interleaved M, M=64/wave:
// 4 chunks of 16 rows share each B-frag. A-frag = one 4B-aligned b128 from
// the parity-matched input copy. grid 2940 x 256. No LDS.
// R9 software pipeline + (256,4) cap kept (null but harmless).
// ---------------------------------------------------------------------------
__global__ __launch_bounds__(256, 4) void conv1_mfma(
    const unsigned short* __restrict__ in16,   // ina; inb = ina + IN16_ELEMS
    const unsigned short* __restrict__ bp1,
    unsigned short* __restrict__ spk16)
{
  const int tid = threadIdx.x;
  const int wave = tid >> 6, lane = tid & 63;
  const int quad = lane >> 4, nl = lane & 15;
  const int m0 = blockIdx.x * 256 + wave * 64;

  // parity of x0 is lane-constant: p = nl & 1 (m0, c*16 even)
  const unsigned short* base = in16 + ((nl & 1) ? (IN16_ELEMS - 1) : 0);

  unsigned o_q[4], o_a[4], o_b[4];
  #pragma unroll
  for (int c = 0; c < 4; ++c) {
    const int m = m0 + c * 16 + nl;
    const int sub = m & 3, g = m >> 2;
    const int gx = g % 112, t = g / 112;
    const int gy = t % 112, n = t / 112;
    const int y0 = gy * 2 + (sub >> 1);        // padded coords
    const int x0 = gx * 2 + (sub & 1);
    const unsigned nb = (unsigned)n * 311904u; // 6*51984
    o_q[c] = nb + (unsigned)((y0 + quad) * 228 + x0);
    o_a[c] = nb + (unsigned)quad * 51984u + (unsigned)((y0 + 4) * 228 + x0);
    o_b[c] = nb + (unsigned)(4 + (quad & 1)) * 51984u + (unsigned)((y0 + 4) * 228 + x0);
  }

  f32x4 acc[4][2];
  #pragma unroll
  for (int c = 0; c < 4; ++c) {
    acc[c][0] = (f32x4){0.f, 0.f, 0.f, 0.f};
    acc[c][1] = (f32x4){0.f, 0.f, 0.f, 0.f};
  }

  const half8* bptr = (const half8*)bp1;

  #define AOFF(s, c) ((s) < 6 ? (o_q[c] + (unsigned)(s) * 51984u) \
                              : ((s) == 6 ? o_a[c] : o_b[c]))
  half8 acur[4], anxt[4];
  #pragma unroll
  for (int c = 0; c < 4; ++c)
    acur[c] = *(const half8u*)(base + AOFF(0, c));

  #pragma unroll
  for (int s = 0; s < 8; ++s) {
    if (s < 7) {
      #pragma unroll
      for (int c = 0; c < 4; ++c)
        anxt[c] = *(const half8u*)(base + AOFF(s + 1, c));
    }
    const half8 b0 = bptr[(s * 2 + 0) * 64 + lane];
    const half8 b1 = bptr[(s * 2 + 1) * 64 + lane];
    #pragma unroll
    for (int c = 0; c < 4; ++c) {
      acc[c][0] = __builtin_amdgcn_mfma_f32_16x16x32_f16(acur[c], b0, acc[c][0], 0, 0, 0);
      acc[c][1] = __builtin_amdgcn_mfma_f32_16x16x32_f16(acur[c], b1, acc[c][1], 0, 0, 0);
    }
    if (s < 7) {
      #pragma unroll
      for (int c = 0; c < 4; ++c) acur[c] = anxt[c];
    }
  }
  #undef AOFF

  #pragma unroll
  for (int c = 0; c < 4; ++c) {
    const int gq = ((m0 + c * 16) >> 2) + quad;
    const int pgx = gq % 112, tq = gq / 112;
    const int pgy = tq % 112, nq = tq / 112;
    const bool f0 = (acc[c][0][0] > POT1_T) | (acc[c][0][1] > POT1_T) |
                    (acc[c][0][2] > POT1_T) | (acc[c][0][3] > POT1_T);
    const bool f1 = (acc[c][1][0] > POT1_T) | (acc[c][1][1] > POT1_T) |
                    (acc[c][1][2] > POT1_T) | (acc[c][1][3] > POT1_T);
    const size_t o = ((size_t)(nq * 114 + pgy + 1) * 114 + (pgx + 1)) * 32 + nl;
    spk16[o] = f0 ? (unsigned short)0x3C00 : (unsigned short)0;
    // ch nl+16: 30/31 (nl>=14) are always zero — written unconditionally so
    // the whole interior is produced here (prep only zeroes the pad ring).
    spk16[o + 16] = (nl < 14 && f1) ? (unsigned short)0x3C00 : (unsigned short)0;
  }
}

// ---------------------------------------------------------------------------
// conv2 + fire. R17: N = 3 subtiles (48 ch), gridDim.y = 5 covers 240.
// B staged in LDS (27.6 KB) -> 5 blocks/CU (was 3 at 46 KB). Each
// ds_read_b128 of B feeds 4 MFMAs. grid (735, 5) x 256.
// R5 epilogue: per u-subtile LDS transpose; every store = one 1KB run.
// R11/R12: nontemporal output stores.
// ---------------------------------------------------------------------------
#define C2_NSUB 3
#define TPAD 258   // f32 stride per ch row: even (b64-aligned)
__global__ __launch_bounds__(256, 5) void conv2_mfma(
    const unsigned short* __restrict__ spk16,
    const unsigned short* __restrict__ bp2,
    float* __restrict__ out_spk, float* __restrict__ out_pot)
{
  // 27648 B; T (16*TPAD*4 = 16512 B) reuses this after the MFMA loop.
  __shared__ __attribute__((aligned(16))) unsigned short Blds[C2_NSUB * 9 * 64 * 8];

  const int tid = threadIdx.x;
  const int ntile = blockIdx.y;                // 0..4, subtiles ntile*3..+2
  // stage 3 subtiles x 9 steps x 64 lanes x 16B = 1728 uint4
  for (int i = tid; i < 1728; i += 256) {
    const int su = i / 576, rem = i - su * 576;    // rem = s*64+lane
    ((uint4*)Blds)[su * 576 + rem] =
        ((const uint4*)bp2)[((rem >> 6) * 15 + ntile * C2_NSUB + su) * 64 + (rem & 63)];
  }
  __syncthreads();

  const int wave = tid >> 6, lane = tid & 63;
  const int quad = lane >> 4, nl = lane & 15;
  const int bx = blockIdx.x;
  const int m0 = bx * 256 + wave * 64;

  const unsigned short* abase[4];
  #pragma unroll
  for (int c = 0; c < 4; ++c) {
    const int m = m0 + c * 16 + nl;
    const int x = m % 112, t = m / 112;
    const int y = t % 112, n = t / 112;
    abase[c] = spk16 + ((size_t)(n * 114 + y) * 114 + x) * 32 + quad * 8;
  }

  f32x4 acc[4][C2_NSUB];
  #pragma unroll
  for (int c = 0; c < 4; ++c)
    #pragma unroll
    for (int u = 0; u < C2_NSUB; ++u) acc[c][u] = (f32x4){0.f, 0.f, 0.f, 0.f};

  const half8* blds = (const half8*)Blds;
  #pragma unroll
  for (int s = 0; s < 9; ++s) {                // s = ky*3+kx
    const int ky = s / 3, kx = s - ky * 3;     // compile-time under unroll
    half8 a[4];
    #pragma unroll
    for (int c = 0; c < 4; ++c)
      a[c] = *(const half8*)(abase[c] + (ky * 114 + kx) * 32);
    #pragma unroll
    for (int u = 0; u < C2_NSUB; ++u) {
      const half8 b = blds[(u * 9 + s) * 64 + lane];
      #pragma unroll
      for (int c = 0; c < 4; ++c)
        acc[c][u] = __builtin_amdgcn_mfma_f32_16x16x32_f16(a[c], b, acc[c][u], 0, 0, 0);
    }
  }

  // ---- transposed epilogue (R5) + nontemporal stores (R11) ----
  float* T = (float*)Blds;                     // 16 x TPAD f32, reuses Blds
  const int n   = (bx * 256) / 12544;
  const int ip0 = (bx * 256) % 12544;
  const size_t obase = (size_t)n * 240 * 12544 + ip0 + 4 * lane;

  #pragma unroll
  for (int u = 0; u < C2_NSUB; ++u) {
    __syncthreads();                           // prev round's reads done
    #pragma unroll
    for (int c = 0; c < 4; ++c) {
      const int mb = wave * 64 + c * 16 + quad * 4;
      #pragma unroll
      for (int rr = 0; rr < 4; ++rr)
        T[nl * TPAD + mb + rr] = acc[c][u][rr];
    }
    __syncthreads();
    #pragma unroll
    for (int j = 0; j < 4; ++j) {
      const int chl = wave * 4 + j;            // 0..15 across 4 waves
      const int ch  = (ntile * C2_NSUB + u) * 16 + chl;
      const f32x2 lo = *(const f32x2*)&T[chl * TPAD + 4 * lane];
      const f32x2 hi = *(const f32x2*)&T[chl * TPAD + 4 * lane + 2];
      f32x4 pt, sp;
      pt[0] = lo[0]; pt[1] = lo[1]; pt[2] = hi[0]; pt[3] = hi[1];
      #pragma unroll
      for (int rr = 0; rr < 4; ++rr) {
        const bool f = pt[rr] > POT2_T;
        sp[rr] = f ? 1.0f : 0.0f;
        pt[rr] = f ? pt[rr] : 0.0f;
      }
      const size_t o = obase + (size_t)ch * 12544;
      __builtin_nontemporal_store(sp, (f32x4*)(out_spk + o));
      __builtin_nontemporal_store(pt, (f32x4*)(out_pot + o));
    }
  }
}

// ---------------------------------------------------------------------------
extern "C" void kernel_launch(void* const* d_in, const int* in_sizes, int n_in,
                              void* d_out, int out_size, void* d_ws, size_t ws_size,
                              hipStream_t stream)
{
  const float* in = (const float*)d_in[0];
  const float* w1 = (const float*)d_in[1];
  const float* w2 = (const float*)d_in[2];
  float* out = (float*)d_out;

  unsigned short* spk16 = (unsigned short*)d_ws;
  unsigned short* bp2   = (unsigned short*)((char*)d_ws + BP2_OFF);
  unsigned short* bp1   = (unsigned short*)((char*)d_ws + BP1_OFF);
  unsigned short* ina   = (unsigned short*)((char*)d_ws + IN16_OFF);

  prep<<<PADROW_BLOCKS + RING_BLOCKS + 151, 256, 0, stream>>>(
      in, w1, w2, ina, bp2, bp1, spk16);
  conv1_mfma<<<2940, 256, 0, stream>>>(ina, bp1, spk16);
  conv2_mfma<<<dim3(735, 5), 256, 0, stream>>>(
      spk16, bp2, out, out + (size_t)15 * 240 * 112 * 112);
}

// Round 18
// 126.015 us; speedup vs baseline: 1.0657x; 1.0252x over previous
//
#include <hip/hip_runtime.h>
#include <stdint.h>

// SNN forward (Mozafari 2018), max_layer==2:
//   pad(2) -> conv1(30,6,5,5) -> fire(>15) -> maxpool2x2 -> pad(1)
//   -> conv2(240,30,3,3) -> fire(>10) -> out = spk ++ pot (f32)
//
// FINAL CONFIG (= R15, best measured 126.5 us). History:
// R1: no hipMemsetAsync. R2: ring-only zero. R3 probe: conv2 ~114 us.
// R4: XCD swizzle regressed. R5: transposed epilogue -33.5 -> 132.6.
// R6/R7: conv2 A-in-LDS regressed. R8 probe: conv1 ~32 us.
// R9: conv1 SW-pipeline + (256,4): null (kept, harmless).
// R10 probe: conv2 memory-bound; write stream thrashed caches.
// R11/R12: conv2 NT stores: -4.2 -> 128.4.
// R13 probe: conv1 latency-bound scatter, no pipe >16% (structural).
// R14: conv2 B-from-global regressed (B-LDS load-bearing).
// R15: prep vectorized 4-wide: -1.9 -> 126.5 (BEST).
// R16: conv1 M=128/wave regressed (+7.8). R17: C2_NSUB=3 regressed (+2.7).
// Ledger: conv2 ~76 (390MB @ ~5.1 TB/s mixed), conv1 ~33 (latency-bound),
// prep+gaps ~17. Decomposition floor ~107; all residuals rejected >=2
// mechanism-backed attempts each.

typedef _Float16 half8  __attribute__((ext_vector_type(8)));
typedef _Float16 half8u __attribute__((ext_vector_type(8), aligned(4)));
typedef float f32x4  __attribute__((ext_vector_type(4)));
typedef float f32x4u __attribute__((ext_vector_type(4), aligned(4)));
typedef float f32x2  __attribute__((ext_vector_type(2)));
typedef short s16x4  __attribute__((ext_vector_type(4)));
typedef short s16x4u __attribute__((ext_vector_type(4), aligned(2)));

#define POT1_T 15.0f
#define POT2_T 10.0f

// ---- ws layout (all 16B aligned) ----
#define SPK_ELEMS  (15*114*114*32)            // 6,238,080 f16 (ch-interleaved, padded)
#define SPK_BYTES  (SPK_ELEMS*2)              // 12,476,160
#define BP2_OFF    SPK_BYTES
#define BP2_BYTES  (9*15*64*8*2)              // 138,240
#define BP1_OFF    (BP2_OFF + BP2_BYTES)
#define BP1_BYTES  (8*2*64*8*2)               // 16,384
#define IN16_OFF   (BP1_OFF + BP1_BYTES)      // 12,630,784 (16B aligned)
#define IN16_ELEMS (90*228*228)               // 4,678,560 f16 per copy
// ina at IN16_OFF; inb (shifted copy) right after; +16B guard. ~31.3 MB total.

#define ROWS_TOTAL (90*228)                   // 20,520 padded rows
#define PADROW_BLOCKS (ROWS_TOTAL/4)          // 5130 (4 waves/block, 1 row/wave)
// pool-pad ring of spike map: 452 positions/image x 32 ch x 15 images
#define RING_ELEMS (15*452*32)                // 216,960
#define RING_BLOCKS ((RING_ELEMS + 255) / 256) // 848

__device__ __forceinline__ unsigned short f2h(float v) {
  union { _Float16 h; unsigned short u; } c;
  c.h = (_Float16)v;                          // RNE
  return c.u;
}

// ---------------------------------------------------------------------------
// prep: pad input -> f16 dual copies (ina[i]=v(i), inb[i-1]=v(i)), zero the
// spike-map pad ring, weight packing to MFMA B-frag layout.
// R15: pad path is one WAVE per padded row; lane l covers xx = 4l..4l+3.
// ---------------------------------------------------------------------------
__global__ __launch_bounds__(256) void prep(
    const float* __restrict__ in, const float* __restrict__ w1,
    const float* __restrict__ w2, unsigned short* __restrict__ ina,
    unsigned short* __restrict__ bp2, unsigned short* __restrict__ bp1,
    unsigned short* __restrict__ spk16)
{
  const int blk = blockIdx.x;
  if (blk < PADROW_BLOCKS) {
    const int wave = threadIdx.x >> 6, l = threadIdx.x & 63;
    if (l >= 57) return;                      // 57 lanes cover 228 = 57*4
    const int row = blk * 4 + wave;           // padded row index (c*228+yy)
    const int c = row / 228, yy = row % 228;
    const int xx0 = l * 4;
    const int rowbase = row * 228;
    s16x4 h4 = (s16x4){0, 0, 0, 0};
    if (yy >= 2 && yy < 226) {
      const float* src = in + ((c * 224 + (yy - 2)) * 224) - 2;  // src[xx]=in[..,xx-2]
      if (l >= 1 && l <= 55) {
        const f32x4u v = *(const f32x4u*)(src + xx0);
        #pragma unroll
        for (int j = 0; j < 4; ++j) h4[j] = (short)f2h(v[j]);
      } else {                                // l==0 (xx 0..3) or l==56 (xx 224..227)
        #pragma unroll
        for (int j = 0; j < 4; ++j) {
          const int xx = xx0 + j;
          if (xx >= 2 && xx < 226) h4[j] = (short)f2h(src[xx]);
        }
      }
    }
    unsigned short* inb = ina + IN16_ELEMS;
    *(s16x4*)(ina + rowbase + xx0) = h4;
    if (row == 0 && l == 0) {                 // avoid inb[-1]
      inb[0] = (unsigned short)h4[1];
      inb[1] = (unsigned short)h4[2];
      inb[2] = (unsigned short)h4[3];
    } else {
      *(s16x4u*)(inb + rowbase + xx0 - 1) = h4;
    }
    if (row == ROWS_TOTAL - 1 && l == 56) inb[IN16_ELEMS - 1] = 0;
    return;
  }
  if (blk < PADROW_BLOCKS + RING_BLOCKS) {    // zero the pool-pad ring only
    const int i = (blk - PADROW_BLOCKS) * 256 + threadIdx.x;
    if (i >= RING_ELEMS) return;
    const int ch = i & 31, t = i >> 5;
    const int p = t % 452, n = t / 452;
    int y, x;
    if (p < 114)      { y = 0;       x = p; }
    else if (p < 228) { y = 113;     x = p - 114; }
    else if (p < 340) { y = p - 227; x = 0; }     // y = 1..112
    else              { y = p - 339; x = 113; }   // y = 1..112
    spk16[((size_t)(n * 114 + y) * 114 + x) * 32 + ch] = 0;
    return;
  }
  if (threadIdx.x >= 64) return;
  const int b = blk - PADROW_BLOCKS - RING_BLOCKS; // 0..150
  const int lane = threadIdx.x;
  const int quad = lane >> 4, nl = lane & 15;
  if (b < 135) {                               // conv2: 9 steps x 15 nsub
    const int s = b / 15, nsub = b - s * 15;   // s = ky*3+kx
    const int ch = nsub * 16 + nl;
    unsigned short* dst = bp2 + (((s * 15 + nsub) * 64 + lane) << 3);
    #pragma unroll
    for (int j = 0; j < 8; ++j) {
      const int ci = quad * 8 + j;
      dst[j] = f2h((ci < 30) ? w2[ch * 270 + ci * 9 + s] : 0.0f);
    }
  } else {                                     // conv1: 8 steps x 2 nsub
    const int bb = b - 135;
    const int s = bb >> 1, nsub = bb & 1;
    const int ch = nsub * 16 + nl;
    unsigned short* dst = bp1 + (((s * 2 + nsub) * 64 + lane) << 3);
    #pragma unroll
    for (int j = 0; j < 8; ++j) {
      int ci, ky;
      bool ok = (ch < 30) && (j < 5);
      if (s < 6)       { ci = s;        ky = quad; }
      else if (s == 6) { ci = quad;     ky = 4;    }
      else             { ci = 4 + quad; ky = 4; ok = ok && (quad < 2); }
      float v = 0.0f;
      if (ok) v = w1[ch * 150 + ci * 25 + ky * 5 + j];
      dst[j] = f2h(v);
    }
  }
}

// ---------------------------------------------------------------------------
// conv1 + fire + maxpool2x2 (R15-exact). Pool-interleaved M, M=64/wave:
// 4 chunks of 16 rows share each B-frag. A-frag = one 4B-aligned b128 from
// the parity-matched input copy (parity = nl&1). grid 2940 x 256. No LDS.
// ---------------------------------------------------------------------------
__global__ __launch_bounds__(256, 4) void conv1_mfma(
    const unsigned short* __restrict__ in16,   // ina; inb = ina + IN16_ELEMS
    const unsigned short* __restrict__ bp1,
    unsigned short* __restrict__ spk16)
{
  const int tid = threadIdx.x;
  const int wave = tid >> 6, lane = tid & 63;
  const int quad = lane >> 4, nl = lane & 15;
  const int m0 = blockIdx.x * 256 + wave * 64;

  // parity of x0 is lane-constant: p = nl & 1 (m0, c*16 even)
  const unsigned short* base = in16 + ((nl & 1) ? (IN16_ELEMS - 1) : 0);

  unsigned o_q[4], o_a[4], o_b[4];
  #pragma unroll
  for (int c = 0; c < 4; ++c) {
    const int m = m0 + c * 16 + nl;
    const int sub = m & 3, g = m >> 2;
    const int gx = g % 112, t = g / 112;
    const int gy = t % 112, n = t / 112;
    const int y0 = gy * 2 + (sub >> 1);        // padded coords
    const int x0 = gx * 2 + (sub & 1);
    const unsigned nb = (unsigned)n * 311904u; // 6*51984
    o_q[c] = nb + (unsigned)((y0 + quad) * 228 + x0);
    o_a[c] = nb + (unsigned)quad * 51984u + (unsigned)((y0 + 4) * 228 + x0);
    o_b[c] = nb + (unsigned)(4 + (quad & 1)) * 51984u + (unsigned)((y0 + 4) * 228 + x0);
  }

  f32x4 acc[4][2];
  #pragma unroll
  for (int c = 0; c < 4; ++c) {
    acc[c][0] = (f32x4){0.f, 0.f, 0.f, 0.f};
    acc[c][1] = (f32x4){0.f, 0.f, 0.f, 0.f};
  }

  const half8* bptr = (const half8*)bp1;

  #define AOFF(s, c) ((s) < 6 ? (o_q[c] + (unsigned)(s) * 51984u) \
                              : ((s) == 6 ? o_a[c] : o_b[c]))
  half8 acur[4], anxt[4];
  #pragma unroll
  for (int c = 0; c < 4; ++c)
    acur[c] = *(const half8u*)(base + AOFF(0, c));

  #pragma unroll
  for (int s = 0; s < 8; ++s) {
    if (s < 7) {
      #pragma unroll
      for (int c = 0; c < 4; ++c)
        anxt[c] = *(const half8u*)(base + AOFF(s + 1, c));
    }
    const half8 b0 = bptr[(s * 2 + 0) * 64 + lane];
    const half8 b1 = bptr[(s * 2 + 1) * 64 + lane];
    #pragma unroll
    for (int c = 0; c < 4; ++c) {
      acc[c][0] = __builtin_amdgcn_mfma_f32_16x16x32_f16(acur[c], b0, acc[c][0], 0, 0, 0);
      acc[c][1] = __builtin_amdgcn_mfma_f32_16x16x32_f16(acur[c], b1, acc[c][1], 0, 0, 0);
    }
    if (s < 7) {
      #pragma unroll
      for (int c = 0; c < 4; ++c) acur[c] = anxt[c];
    }
  }
  #undef AOFF

  #pragma unroll
  for (int c = 0; c < 4; ++c) {
    const int gq = ((m0 + c * 16) >> 2) + quad;
    const int pgx = gq % 112, tq = gq / 112;
    const int pgy = tq % 112, nq = tq / 112;
    const bool f0 = (acc[c][0][0] > POT1_T) | (acc[c][0][1] > POT1_T) |
                    (acc[c][0][2] > POT1_T) | (acc[c][0][3] > POT1_T);
    const bool f1 = (acc[c][1][0] > POT1_T) | (acc[c][1][1] > POT1_T) |
                    (acc[c][1][2] > POT1_T) | (acc[c][1][3] > POT1_T);
    const size_t o = ((size_t)(nq * 114 + pgy + 1) * 114 + (pgx + 1)) * 32 + nl;
    spk16[o] = f0 ? (unsigned short)0x3C00 : (unsigned short)0;
    // ch nl+16: 30/31 (nl>=14) are always zero — written unconditionally so
    // the whole interior is produced here (prep only zeroes the pad ring).
    spk16[o + 16] = (nl < 14 && f1) ? (unsigned short)0x3C00 : (unsigned short)0;
  }
}

// ---------------------------------------------------------------------------
// conv2 + fire (R12 form — locked): block = 4 waves x M=256 rows; N = 5
// subtiles (80 ch), gridDim.y = 3. B staged in LDS (46 KB); each
// ds_read_b128 of B feeds 4 MFMAs. grid (735, 3) x 256.
// R5 epilogue: per u-subtile LDS transpose; every store = one 1KB run.
// R11/R12: nontemporal output stores.
// ---------------------------------------------------------------------------
#define C2_NSUB 5
#define TPAD 258   // f32 stride per ch row: even (b64-aligned)
__global__ __launch_bounds__(256, 3) void conv2_mfma(
    const unsigned short* __restrict__ spk16,
    const unsigned short* __restrict__ bp2,
    float* __restrict__ out_spk, float* __restrict__ out_pot)
{
  __shared__ __attribute__((aligned(16))) unsigned short Blds[C2_NSUB * 9 * 64 * 8];

  const int tid = threadIdx.x;
  const int ntile = blockIdx.y;                // 0..2, subtiles ntile*5..+4
  // stage 5 subtiles x 9 steps x 64 lanes x 16B = 2880 uint4
  for (int i = tid; i < 2880; i += 256) {
    const int su = i / 576, rem = i - su * 576;    // rem = s*64+lane
    ((uint4*)Blds)[su * 576 + rem] =
        ((const uint4*)bp2)[((rem >> 6) * 15 + ntile * C2_NSUB + su) * 64 + (rem & 63)];
  }
  __syncthreads();

  const int wave = tid >> 6, lane = tid & 63;
  const int quad = lane >> 4, nl = lane & 15;
  const int bx = blockIdx.x;
  const int m0 = bx * 256 + wave * 64;

  const unsigned short* abase[4];
  #pragma unroll
  for (int c = 0; c < 4; ++c) {
    const int m = m0 + c * 16 + nl;
    const int x = m % 112, t = m / 112;
    const int y = t % 112, n = t / 112;
    abase[c] = spk16 + ((size_t)(n * 114 + y) * 114 + x) * 32 + quad * 8;
  }

  f32x4 acc[4][C2_NSUB];
  #pragma unroll
  for (int c = 0; c < 4; ++c)
    #pragma unroll
    for (int u = 0; u < C2_NSUB; ++u) acc[c][u] = (f32x4){0.f, 0.f, 0.f, 0.f};

  const half8* blds = (const half8*)Blds;
  #pragma unroll
  for (int s = 0; s < 9; ++s) {                // s = ky*3+kx
    const int ky = s / 3, kx = s - ky * 3;     // compile-time under unroll
    half8 a[4];
    #pragma unroll
    for (int c = 0; c < 4; ++c)
      a[c] = *(const half8*)(abase[c] + (ky * 114 + kx) * 32);
    #pragma unroll
    for (int u = 0; u < C2_NSUB; ++u) {
      const half8 b = blds[(u * 9 + s) * 64 + lane];
      #pragma unroll
      for (int c = 0; c < 4; ++c)
        acc[c][u] = __builtin_amdgcn_mfma_f32_16x16x32_f16(a[c], b, acc[c][u], 0, 0, 0);
    }
  }

  // ---- transposed epilogue (R5) + nontemporal stores (R11) ----
  float* T = (float*)Blds;                     // 16 x TPAD f32, reuses Blds
  const int n   = (bx * 256) / 12544;
  const int ip0 = (bx * 256) % 12544;
  const size_t obase = (size_t)n * 240 * 12544 + ip0 + 4 * lane;

  #pragma unroll
  for (int u = 0; u < C2_NSUB; ++u) {
    __syncthreads();                           // prev round's reads done
    #pragma unroll
    for (int c = 0; c < 4; ++c) {
      const int mb = wave * 64 + c * 16 + quad * 4;
      #pragma unroll
      for (int rr = 0; rr < 4; ++rr)
        T[nl * TPAD + mb + rr] = acc[c][u][rr];
    }
    __syncthreads();
    #pragma unroll
    for (int j = 0; j < 4; ++j) {
      const int chl = wave * 4 + j;            // 0..15 across 4 waves
      const int ch  = (ntile * C2_NSUB + u) * 16 + chl;
      const f32x2 lo = *(const f32x2*)&T[chl * TPAD + 4 * lane];
      const f32x2 hi = *(const f32x2*)&T[chl * TPAD + 4 * lane + 2];
      f32x4 pt, sp;
      pt[0] = lo[0]; pt[1] = lo[1]; pt[2] = hi[0]; pt[3] = hi[1];
      #pragma unroll
      for (int rr = 0; rr < 4; ++rr) {
        const bool f = pt[rr] > POT2_T;
        sp[rr] = f ? 1.0f : 0.0f;
        pt[rr] = f ? pt[rr] : 0.0f;
      }
      const size_t o = obase + (size_t)ch * 12544;
      __builtin_nontemporal_store(sp, (f32x4*)(out_spk + o));
      __builtin_nontemporal_store(pt, (f32x4*)(out_pot + o));
    }
  }
}

// ---------------------------------------------------------------------------
extern "C" void kernel_launch(void* const* d_in, const int* in_sizes, int n_in,
                              void* d_out, int out_size, void* d_ws, size_t ws_size,
                              hipStream_t stream)
{
  const float* in = (const float*)d_in[0];
  const float* w1 = (const float*)d_in[1];
  const float* w2 = (const float*)d_in[2];
  float* out = (float*)d_out;

  unsigned short* spk16 = (unsigned short*)d_ws;
  unsigned short* bp2   = (unsigned short*)((char*)d_ws + BP2_OFF);
  unsigned short* bp1   = (unsigned short*)((char*)d_ws + BP1_OFF);
  unsigned short* ina   = (unsigned short*)((char*)d_ws + IN16_OFF);

  prep<<<PADROW_BLOCKS + RING_BLOCKS + 151, 256, 0, stream>>>(
      in, w1, w2, ina, bp2, bp1, spk16);
  conv1_mfma<<<2940, 256, 0, stream>>>(ina, bp1, spk16);
  conv2_mfma<<<dim3(735, 3), 256, 0, stream>>>(
      spk16, bp2, out, out + (size_t)15 * 240 * 112 * 112);
}